// Round 1
// baseline (1048.051 us; speedup 1.0000x reference)
//
#include <hip/hip_runtime.h>

typedef unsigned int u32;

static constexpr int HH = 1080, WW = 1920, CC = 3;
static constexpr int NPIX = HH * WW;
static constexpr int NQ = 17;  // supports split <= 16 (actual split = 10)

// workspace layout (bytes)
static constexpr size_t CTRL_OFF  = 0;                               // u32[1]: valid count
static constexpr size_t MIDS_OFF  = 256;                             // float[32]
static constexpr size_t QBIN_OFF  = 384;                             // u32[32]
static constexpr size_t QRANK_OFF = 512;                             // u32[32]
static constexpr size_t HIST1_OFF = 1024;                            // u32[65536]
static constexpr size_t HIST2_OFF = HIST1_OFF + 65536ull * 4;        // u32[NQ*65536]
static constexpr size_t PRIO_OFF  = HIST2_OFF + (size_t)NQ * 65536 * 4; // u32[NPIX]
static constexpr size_t WS_NEED   = PRIO_OFF + (size_t)NPIX * 4;

// ---- pass 1: histogram of high 16 bits of float bit pattern + valid count ----
__global__ void k_hist1(const float* __restrict__ depth, u32* __restrict__ hist1,
                        u32* __restrict__ cnt) {
    int i = blockIdx.x * blockDim.x + threadIdx.x;
    if (i >= NPIX) return;
    float d = depth[i];
    if (d == 100.0f) return;              // invalid sentinel: excluded from sort
    u32 bits = __float_as_uint(d);        // depth > 0 -> bits monotonic with value
    atomicAdd(&hist1[bits >> 16], 1u);
    atomicAdd(cnt, 1u);
}

// ---- pass 2: find (bin, rank-within-bin) for each needed order statistic ----
__global__ __launch_bounds__(1024) void k_select1(const u32* __restrict__ hist1,
                                                  const u32* __restrict__ cnt,
                                                  const int* __restrict__ splitp,
                                                  u32* __restrict__ qbin,
                                                  u32* __restrict__ qrank) {
    __shared__ u32 part[1024];
    int tid = threadIdx.x;
    int split = *splitp;
    u32 l = *cnt;
    u32 step = l / (u32)split;
    u32 local = 0;
    int base = tid * 64;
    for (int j = 0; j < 64; ++j) local += hist1[base + j];
    part[tid] = local;
    __syncthreads();
    for (int off = 1; off < 1024; off <<= 1) {
        u32 v = (tid >= off) ? part[tid - off] : 0;
        __syncthreads();
        part[tid] += v;
        __syncthreads();
    }
    u32 cum = part[tid] - local;  // exclusive prefix of this thread's 64 bins
    for (int j = 0; j < 64; ++j) {
        u32 c = hist1[base + j];
        if (c) {
            for (int q = 0; q <= split; ++q) {
                u32 r = (q < split) ? (u32)q * step : l - 1u;
                if (r >= cum && r < cum + c) { qbin[q] = (u32)(base + j); qrank[q] = r - cum; }
            }
        }
        cum += c;
    }
}

// ---- pass 3: low-16-bit histogram restricted to each query's high bin ----
__global__ void k_hist2(const float* __restrict__ depth, const int* __restrict__ splitp,
                        const u32* __restrict__ qbin, u32* __restrict__ hist2) {
    int i = blockIdx.x * blockDim.x + threadIdx.x;
    if (i >= NPIX) return;
    float d = depth[i];
    if (d == 100.0f) return;
    u32 bits = __float_as_uint(d);
    u32 hi = bits >> 16, lo = bits & 0xFFFFu;
    int split = *splitp;
    for (int q = 0; q <= split; ++q)
        if (qbin[q] == hi) atomicAdd(&hist2[q * 65536 + lo], 1u);
}

// ---- pass 4: resolve exact order-statistic values (the bin midpoints) ----
__global__ __launch_bounds__(1024) void k_select2(const u32* __restrict__ hist2,
                                                  const int* __restrict__ splitp,
                                                  const u32* __restrict__ qbin,
                                                  const u32* __restrict__ qrank,
                                                  float* __restrict__ mids) {
    int q = blockIdx.x;
    int split = *splitp;
    if (q > split) return;
    const u32* h = hist2 + q * 65536;
    u32 target = qrank[q];
    __shared__ u32 part[1024];
    int tid = threadIdx.x;
    u32 local = 0;
    int base = tid * 64;
    for (int j = 0; j < 64; ++j) local += h[base + j];
    part[tid] = local;
    __syncthreads();
    for (int off = 1; off < 1024; off <<= 1) {
        u32 v = (tid >= off) ? part[tid - off] : 0;
        __syncthreads();
        part[tid] += v;
        __syncthreads();
    }
    u32 cum = part[tid] - local;
    for (int j = 0; j < 64; ++j) {
        u32 c = h[base + j];
        if (c && target >= cum && target < cum + c)
            mids[q] = __uint_as_float((qbin[q] << 16) | (u32)(base + j));
        cum += c;
    }
}

// shared splat-geometry helper: returns priority p>0 and target t, or 0 if dropped
__device__ __forceinline__ u32 splat_calc(int i, float d, const float* __restrict__ flow,
                                          const float* __restrict__ mids, int split,
                                          int* __restrict__ tgt) {
    int rank = -1;
    for (int k = 1; k <= split; ++k) {
        if (d >= mids[k - 1] && d < mids[k]) { rank = split - k; break; }
    }
    if (rank < 0) return 0;  // includes d == max (strict <) and d == 100 sentinel
    int y = i / WW, x = i - y * WW;
    float fx = flow[2 * i + 0], fy = flow[2 * i + 1];
    int ty = (int)rintf((float)y + fy);  // rintf = round-half-even = jnp.round
    int tx = (int)rintf((float)x + fx);
    if (ty < 0) ty += HH;                // JAX normalizes negative indices once
    if (tx < 0) tx += WW;
    if ((unsigned)ty >= (unsigned)HH || (unsigned)tx >= (unsigned)WW) return 0;  // mode='drop'
    *tgt = ty * WW + tx;
    // far bins first (rank 0), near bins later (rank split-1); within bin, last
    // row-major source wins (XLA CPU scatter-set order)
    return (u32)rank * (u32)NPIX + (u32)i + 1u;
}

// ---- pass 5: per-target max-priority via atomicMax ----
__global__ void k_prio(const float* __restrict__ depth, const float* __restrict__ flow,
                       const int* __restrict__ splitp, const float* __restrict__ mids,
                       u32* __restrict__ prio) {
    int i = blockIdx.x * blockDim.x + threadIdx.x;
    if (i >= NPIX) return;
    int split = *splitp;
    int t;
    u32 p = splat_calc(i, depth[i], flow, mids, split, &t);
    if (p) atomicMax(&prio[t], p);
}

// ---- pass 6: unique winner writes its 3 channels ----
__global__ void k_write(const float* __restrict__ depth, const float* __restrict__ flow,
                        const float* __restrict__ img, const int* __restrict__ splitp,
                        const float* __restrict__ mids, const u32* __restrict__ prio,
                        float* __restrict__ out) {
    int i = blockIdx.x * blockDim.x + threadIdx.x;
    if (i >= NPIX) return;
    int split = *splitp;
    int t;
    u32 p = splat_calc(i, depth[i], flow, mids, split, &t);
    if (p && prio[t] == p) {
        out[t * 3 + 0] = img[i * 3 + 0];
        out[t * 3 + 1] = img[i * 3 + 1];
        out[t * 3 + 2] = img[i * 3 + 2];
    }
}

extern "C" void kernel_launch(void* const* d_in, const int* in_sizes, int n_in,
                              void* d_out, int out_size, void* d_ws, size_t ws_size,
                              hipStream_t stream) {
    const float* img   = (const float*)d_in[0];
    const float* flow  = (const float*)d_in[1];   // [1,H,W,2] -> same flat layout as [H,W,2]
    const float* depth = (const float*)d_in[2];
    const int*   splitp = (const int*)d_in[3];

    char* ws = (char*)d_ws;
    u32*   ctrl  = (u32*)(ws + CTRL_OFF);
    float* mids  = (float*)(ws + MIDS_OFF);
    u32*   qbin  = (u32*)(ws + QBIN_OFF);
    u32*   qrank = (u32*)(ws + QRANK_OFF);
    u32*   hist1 = (u32*)(ws + HIST1_OFF);
    u32*   hist2 = (u32*)(ws + HIST2_OFF);
    u32*   prio  = (u32*)(ws + PRIO_OFF);
    float* out   = (float*)d_out;

    // zero all scratch (hists, count, priorities) and the output each call
    hipMemsetAsync(d_ws, 0, WS_NEED, stream);
    hipMemsetAsync(d_out, 0, (size_t)out_size * sizeof(float), stream);

    int blocks = (NPIX + 255) / 256;
    k_hist1  <<<blocks, 256, 0, stream>>>(depth, hist1, ctrl);
    k_select1<<<1, 1024, 0, stream>>>(hist1, ctrl, splitp, qbin, qrank);
    k_hist2  <<<blocks, 256, 0, stream>>>(depth, splitp, qbin, hist2);
    k_select2<<<NQ, 1024, 0, stream>>>(hist2, splitp, qbin, qrank, mids);
    k_prio   <<<blocks, 256, 0, stream>>>(depth, flow, splitp, mids, prio);
    k_write  <<<blocks, 256, 0, stream>>>(depth, flow, img, splitp, mids, prio, out);
}

// Round 2
// 236.289 us; speedup vs baseline: 4.4355x; 4.4355x over previous
//
#include <hip/hip_runtime.h>

typedef unsigned int u32;

static constexpr int HH = 1080, WW = 1920;
static constexpr int NPIX = HH * WW;
static constexpr int NQ = 17;        // supports split <= 16 (actual split = 10)
static constexpr int NBLK_A = 128;   // grid-stride blocks for level-1 histogram

// ---- workspace layout (bytes, 256-aligned regions) ----
static constexpr size_t MIDS_OFF  = 0;        // float[32]
static constexpr size_t QB1_OFF   = 128;      // u32[32]
static constexpr size_t QR1_OFF   = 256;      // u32[32]
static constexpr size_t QB2_OFF   = 384;      // u32[32]
static constexpr size_t QR2_OFF   = 512;      // u32[32]
static constexpr size_t TOT1_OFF  = 1024;                          // u32[4096]
static constexpr size_t HIST2_OFF = TOT1_OFF + 4096ull * 4;        // u32[NQ*1024]
static constexpr size_t HIST3_OFF = HIST2_OFF + (size_t)NQ * 1024 * 4;
static constexpr size_t PRIO_OFF  = ((HIST3_OFF + (size_t)NQ * 1024 * 4) + 255) & ~255ull;
static constexpr size_t ZERO_BYTES = PRIO_OFF + (size_t)NPIX * 4;  // memset range

// ---- level 1: LDS-privatized 4096-bin histogram of bits[31:20] ----
__global__ __launch_bounds__(256) void k_histA(const float* __restrict__ depth,
                                               u32* __restrict__ tot1) {
    __shared__ u32 h[4096];
    for (int j = threadIdx.x; j < 4096; j += 256) h[j] = 0;
    __syncthreads();
    for (int i = blockIdx.x * 256 + threadIdx.x; i < NPIX; i += gridDim.x * 256) {
        float d = depth[i];
        if (d != 100.0f)                                 // sentinel excluded
            atomicAdd(&h[__float_as_uint(d) >> 20], 1u); // d>0 -> bits monotonic
    }
    __syncthreads();
    for (int j = threadIdx.x; j < 4096; j += 256) {
        u32 v = h[j];
        if (v) atomicAdd(&tot1[j], v);   // sparse merge, ~200 occupied bins/block
    }
}

// ---- level-1 select: locate each order statistic's 12-bit bin + in-bin rank ----
__global__ __launch_bounds__(1024) void k_selA(const u32* __restrict__ tot1,
                                               const int* __restrict__ splitp,
                                               u32* __restrict__ qb1, u32* __restrict__ qr1) {
    __shared__ u32 part[1024];
    __shared__ u32 totalsh;
    int tid = threadIdx.x;
    int base = tid * 4;
    u32 c0 = tot1[base], c1 = tot1[base + 1], c2 = tot1[base + 2], c3 = tot1[base + 3];
    u32 local = c0 + c1 + c2 + c3;
    part[tid] = local;
    __syncthreads();
    for (int off = 1; off < 1024; off <<= 1) {
        u32 v = (tid >= off) ? part[tid - off] : 0;
        __syncthreads();
        part[tid] += v;
        __syncthreads();
    }
    if (tid == 1023) totalsh = part[1023];
    __syncthreads();
    u32 l = totalsh;                 // valid-pixel count = sum of histogram
    int split = *splitp;
    u32 step = l / (u32)split;
    u32 cum = part[tid] - local;     // exclusive prefix of this thread's 4 bins
    u32 cc[4] = {c0, c1, c2, c3};
    for (int j = 0; j < 4; ++j) {
        u32 c = cc[j];
        if (c) {
            for (int q = 0; q <= split; ++q) {
                u32 r = (q < split) ? (u32)q * step : l - 1u;
                if (r >= cum && r < cum + c) { qb1[q] = (u32)(base + j); qr1[q] = r - cum; }
            }
        }
        cum += c;
    }
}

// ---- level 2: 1024-bin histogram of bits[19:10], restricted per query ----
__global__ void k_histB(const float* __restrict__ depth, const int* __restrict__ splitp,
                        const u32* __restrict__ qb1, u32* __restrict__ hist2) {
    int i = blockIdx.x * blockDim.x + threadIdx.x;
    if (i >= NPIX) return;
    float d = depth[i];
    if (d == 100.0f) return;
    u32 bits = __float_as_uint(d);
    u32 b1 = bits >> 20, b2 = (bits >> 10) & 1023u;
    int split = *splitp;
    for (int q = 0; q <= split; ++q)
        if (qb1[q] == b1) atomicAdd(&hist2[q * 1024 + b2], 1u);
}

// ---- level-2 select ----
__global__ __launch_bounds__(1024) void k_selB(const u32* __restrict__ hist2,
                                               const int* __restrict__ splitp,
                                               const u32* __restrict__ qr1,
                                               u32* __restrict__ qb2, u32* __restrict__ qr2) {
    int q = blockIdx.x;
    if (q > *splitp) return;
    const u32* h = hist2 + q * 1024;
    u32 target = qr1[q];
    __shared__ u32 part[1024];
    int tid = threadIdx.x;
    u32 local = h[tid];
    part[tid] = local;
    __syncthreads();
    for (int off = 1; off < 1024; off <<= 1) {
        u32 v = (tid >= off) ? part[tid - off] : 0;
        __syncthreads();
        part[tid] += v;
        __syncthreads();
    }
    u32 cum = part[tid] - local;
    if (local && target >= cum && target < cum + local) {
        qb2[q] = (u32)tid;
        qr2[q] = target - cum;
    }
}

// ---- level 3: 1024-bin histogram of bits[9:0], restricted to 22-bit key ----
__global__ void k_histC(const float* __restrict__ depth, const int* __restrict__ splitp,
                        const u32* __restrict__ qb1, const u32* __restrict__ qb2,
                        u32* __restrict__ hist3) {
    int i = blockIdx.x * blockDim.x + threadIdx.x;
    if (i >= NPIX) return;
    float d = depth[i];
    if (d == 100.0f) return;
    u32 bits = __float_as_uint(d);
    u32 hi22 = bits >> 10;
    int split = *splitp;
    for (int q = 0; q <= split; ++q)
        if (((qb1[q] << 10) | qb2[q]) == hi22)
            atomicAdd(&hist3[q * 1024 + (bits & 1023u)], 1u);
}

// ---- level-3 select: exact order-statistic float values ----
__global__ __launch_bounds__(1024) void k_selC(const u32* __restrict__ hist3,
                                               const int* __restrict__ splitp,
                                               const u32* __restrict__ qb1,
                                               const u32* __restrict__ qb2,
                                               const u32* __restrict__ qr2,
                                               float* __restrict__ mids) {
    int q = blockIdx.x;
    if (q > *splitp) return;
    const u32* h = hist3 + q * 1024;
    u32 target = qr2[q];
    __shared__ u32 part[1024];
    int tid = threadIdx.x;
    u32 local = h[tid];
    part[tid] = local;
    __syncthreads();
    for (int off = 1; off < 1024; off <<= 1) {
        u32 v = (tid >= off) ? part[tid - off] : 0;
        __syncthreads();
        part[tid] += v;
        __syncthreads();
    }
    u32 cum = part[tid] - local;
    if (local && target >= cum && target < cum + local)
        mids[q] = __uint_as_float((((qb1[q] << 10) | qb2[q]) << 10) | (u32)tid);
}

// ---- splat geometry: priority p>0 and target t, or 0 if dropped ----
__device__ __forceinline__ u32 splat_calc(int i, float d, const float* __restrict__ flow,
                                          const float* __restrict__ mids, int split,
                                          int* __restrict__ tgt) {
    int rank = -1;
    for (int k = 1; k <= split; ++k) {
        if (d >= mids[k - 1] && d < mids[k]) { rank = split - k; break; }
    }
    if (rank < 0) return 0;  // includes d == max (strict <) and d == 100 sentinel
    int y = i / WW, x = i - y * WW;
    float fx = flow[2 * i + 0], fy = flow[2 * i + 1];
    int ty = (int)rintf((float)y + fy);  // rintf = round-half-even = jnp.round
    int tx = (int)rintf((float)x + fx);
    if (ty < 0) ty += HH;                // JAX normalizes negative indices once
    if (tx < 0) tx += WW;
    if ((unsigned)ty >= (unsigned)HH || (unsigned)tx >= (unsigned)WW) return 0;  // drop
    *tgt = ty * WW + tx;
    // far bins = low rank; near bins = high; within bin, last row-major wins
    return (u32)rank * (u32)NPIX + (u32)i + 1u;
}

__global__ void k_prio(const float* __restrict__ depth, const float* __restrict__ flow,
                       const int* __restrict__ splitp, const float* __restrict__ mids,
                       u32* __restrict__ prio) {
    int i = blockIdx.x * blockDim.x + threadIdx.x;
    if (i >= NPIX) return;
    int split = *splitp;
    int t;
    u32 p = splat_calc(i, depth[i], flow, mids, split, &t);
    if (p) atomicMax(&prio[t], p);
}

__global__ void k_write(const float* __restrict__ depth, const float* __restrict__ flow,
                        const float* __restrict__ img, const int* __restrict__ splitp,
                        const float* __restrict__ mids, const u32* __restrict__ prio,
                        float* __restrict__ out) {
    int i = blockIdx.x * blockDim.x + threadIdx.x;
    if (i >= NPIX) return;
    int split = *splitp;
    int t;
    u32 p = splat_calc(i, depth[i], flow, mids, split, &t);
    if (p && prio[t] == p) {
        out[t * 3 + 0] = img[i * 3 + 0];
        out[t * 3 + 1] = img[i * 3 + 1];
        out[t * 3 + 2] = img[i * 3 + 2];
    }
}

extern "C" void kernel_launch(void* const* d_in, const int* in_sizes, int n_in,
                              void* d_out, int out_size, void* d_ws, size_t ws_size,
                              hipStream_t stream) {
    const float* img    = (const float*)d_in[0];
    const float* flow   = (const float*)d_in[1];   // [1,H,W,2] flat == [H,W,2]
    const float* depth  = (const float*)d_in[2];
    const int*   splitp = (const int*)d_in[3];

    char* ws = (char*)d_ws;
    float* mids  = (float*)(ws + MIDS_OFF);
    u32*   qb1   = (u32*)(ws + QB1_OFF);
    u32*   qr1   = (u32*)(ws + QR1_OFF);
    u32*   qb2   = (u32*)(ws + QB2_OFF);
    u32*   qr2   = (u32*)(ws + QR2_OFF);
    u32*   tot1  = (u32*)(ws + TOT1_OFF);
    u32*   hist2 = (u32*)(ws + HIST2_OFF);
    u32*   hist3 = (u32*)(ws + HIST3_OFF);
    u32*   prio  = (u32*)(ws + PRIO_OFF);
    float* out   = (float*)d_out;

    // zero: query scratch + hists + priorities, and the output image
    hipMemsetAsync(d_ws, 0, ZERO_BYTES, stream);
    hipMemsetAsync(d_out, 0, (size_t)out_size * sizeof(float), stream);

    int blocks = (NPIX + 255) / 256;
    k_histA<<<NBLK_A, 256, 0, stream>>>(depth, tot1);
    k_selA <<<1, 1024, 0, stream>>>(tot1, splitp, qb1, qr1);
    k_histB<<<blocks, 256, 0, stream>>>(depth, splitp, qb1, hist2);
    k_selB <<<NQ, 1024, 0, stream>>>(hist2, splitp, qr1, qb2, qr2);
    k_histC<<<blocks, 256, 0, stream>>>(depth, splitp, qb1, qb2, hist3);
    k_selC <<<NQ, 1024, 0, stream>>>(hist3, splitp, qb1, qb2, qr2, mids);
    k_prio <<<blocks, 256, 0, stream>>>(depth, flow, splitp, mids, prio);
    k_write<<<blocks, 256, 0, stream>>>(depth, flow, img, splitp, mids, prio, out);
}

// Round 3
// 193.822 us; speedup vs baseline: 5.4073x; 1.2191x over previous
//
#include <hip/hip_runtime.h>

typedef unsigned int u32;

static constexpr int HH = 1080, WW = 1920;
static constexpr int NPIX = HH * WW;
static constexpr int NQ = 17;        // supports split <= 16 (actual split = 10)
static constexpr int NBLK_A = 256;   // grid-stride blocks for level-1 histogram
static constexpr int R1 = 16;        // replicas for level-1 merge
static constexpr int R2 = 32;        // replicas for level-2/3 hists

// ---- workspace layout (bytes) ----
static constexpr size_t MIDS_OFF   = 0;      // float[32]
static constexpr size_t QB1_OFF    = 128;    // u32[32]
static constexpr size_t QR1_OFF    = 256;    // u32[32]
static constexpr size_t QB2_OFF    = 384;    // u32[32]
static constexpr size_t QR2_OFF    = 512;    // u32[32]
static constexpr size_t TOT1_OFF   = 1024;                                   // u32[R1*4096]
static constexpr size_t HIST2_OFF  = TOT1_OFF + (size_t)R1 * 4096 * 4;       // u32[R2*NQ*1024]
static constexpr size_t HIST3_OFF  = HIST2_OFF + (size_t)R2 * NQ * 1024 * 4; // u32[R2*NQ*1024]
static constexpr size_t PRIO_OFF   = HIST3_OFF + (size_t)R2 * NQ * 1024 * 4; // u32[NPIX]
static constexpr size_t ZERO_BYTES = PRIO_OFF + (size_t)NPIX * 4;

// ---- level 1: LDS-privatized 4096-bin histogram of bits[31:20] ----
__global__ __launch_bounds__(256) void k_histA(const float* __restrict__ depth,
                                               u32* __restrict__ tot1) {
    __shared__ u32 h[4096];
    for (int j = threadIdx.x; j < 4096; j += 256) h[j] = 0;
    __syncthreads();
    for (int i = blockIdx.x * 256 + threadIdx.x; i < NPIX; i += gridDim.x * 256) {
        float d = depth[i];
        if (d != 100.0f)                                 // sentinel excluded
            atomicAdd(&h[__float_as_uint(d) >> 20], 1u); // d>0 -> bits monotonic
    }
    __syncthreads();
    u32 rep = blockIdx.x & (R1 - 1);
    for (int j = threadIdx.x; j < 4096; j += 256) {
        u32 v = h[j];
        if (v) atomicAdd(&tot1[rep * 4096 + j], v);   // replica-spread sparse merge
    }
}

// ---- level-1 select: locate each order statistic's 12-bit bin + in-bin rank ----
__global__ __launch_bounds__(1024) void k_selA(const u32* __restrict__ tot1,
                                               const int* __restrict__ splitp,
                                               u32* __restrict__ qb1, u32* __restrict__ qr1) {
    __shared__ u32 part[1024];
    __shared__ u32 totalsh;
    int tid = threadIdx.x;
    int base = tid * 4;
    u32 cc[4] = {0, 0, 0, 0};
    for (int r = 0; r < R1; ++r)
        for (int j = 0; j < 4; ++j) cc[j] += tot1[r * 4096 + base + j];
    u32 local = cc[0] + cc[1] + cc[2] + cc[3];
    part[tid] = local;
    __syncthreads();
    for (int off = 1; off < 1024; off <<= 1) {
        u32 v = (tid >= off) ? part[tid - off] : 0;
        __syncthreads();
        part[tid] += v;
        __syncthreads();
    }
    if (tid == 1023) totalsh = part[1023];
    __syncthreads();
    u32 l = totalsh;                 // valid-pixel count = sum of histogram
    int split = *splitp;
    u32 step = l / (u32)split;
    u32 cum = part[tid] - local;     // exclusive prefix of this thread's 4 bins
    for (int j = 0; j < 4; ++j) {
        u32 c = cc[j];
        if (c) {
            for (int q = 0; q <= split; ++q) {
                u32 r = (q < split) ? (u32)q * step : l - 1u;
                if (r >= cum && r < cum + c) { qb1[q] = (u32)(base + j); qr1[q] = r - cum; }
            }
        }
        cum += c;
    }
}

// ---- level 2: 1024-bin histogram of bits[19:10], restricted per query ----
__global__ void k_histB(const float* __restrict__ depth, const int* __restrict__ splitp,
                        const u32* __restrict__ qb1, u32* __restrict__ hist2) {
    int i = blockIdx.x * blockDim.x + threadIdx.x;
    if (i >= NPIX) return;
    float d = depth[i];
    if (d == 100.0f) return;
    u32 bits = __float_as_uint(d);
    u32 b1 = bits >> 20, b2 = (bits >> 10) & 1023u;
    u32 rep = (u32)(threadIdx.x & (R2 - 1));
    int split = *splitp;
    for (int q = 0; q <= split; ++q)
        if (qb1[q] == b1) atomicAdd(&hist2[(rep * NQ + q) * 1024 + b2], 1u);
}

// ---- level-2 select ----
__global__ __launch_bounds__(1024) void k_selB(const u32* __restrict__ hist2,
                                               const int* __restrict__ splitp,
                                               const u32* __restrict__ qr1,
                                               u32* __restrict__ qb2, u32* __restrict__ qr2) {
    int q = blockIdx.x;
    if (q > *splitp) return;
    __shared__ u32 part[1024];
    int tid = threadIdx.x;
    u32 local = 0;
    for (int r = 0; r < R2; ++r) local += hist2[(r * NQ + q) * 1024 + tid];
    part[tid] = local;
    __syncthreads();
    for (int off = 1; off < 1024; off <<= 1) {
        u32 v = (tid >= off) ? part[tid - off] : 0;
        __syncthreads();
        part[tid] += v;
        __syncthreads();
    }
    u32 target = qr1[q];
    u32 cum = part[tid] - local;
    if (local && target >= cum && target < cum + local) {
        qb2[q] = (u32)tid;
        qr2[q] = target - cum;
    }
}

// ---- level 3: 1024-bin histogram of bits[9:0], restricted to 22-bit key ----
__global__ void k_histC(const float* __restrict__ depth, const int* __restrict__ splitp,
                        const u32* __restrict__ qb1, const u32* __restrict__ qb2,
                        u32* __restrict__ hist3) {
    int i = blockIdx.x * blockDim.x + threadIdx.x;
    if (i >= NPIX) return;
    float d = depth[i];
    if (d == 100.0f) return;
    u32 bits = __float_as_uint(d);
    u32 hi22 = bits >> 10;
    u32 rep = (u32)(threadIdx.x & (R2 - 1));
    int split = *splitp;
    for (int q = 0; q <= split; ++q)
        if (((qb1[q] << 10) | qb2[q]) == hi22)
            atomicAdd(&hist3[(rep * NQ + q) * 1024 + (bits & 1023u)], 1u);
}

// ---- level-3 select: exact order-statistic float values ----
__global__ __launch_bounds__(1024) void k_selC(const u32* __restrict__ hist3,
                                               const int* __restrict__ splitp,
                                               const u32* __restrict__ qb1,
                                               const u32* __restrict__ qb2,
                                               const u32* __restrict__ qr2,
                                               float* __restrict__ mids) {
    int q = blockIdx.x;
    if (q > *splitp) return;
    __shared__ u32 part[1024];
    int tid = threadIdx.x;
    u32 local = 0;
    for (int r = 0; r < R2; ++r) local += hist3[(r * NQ + q) * 1024 + tid];
    part[tid] = local;
    __syncthreads();
    for (int off = 1; off < 1024; off <<= 1) {
        u32 v = (tid >= off) ? part[tid - off] : 0;
        __syncthreads();
        part[tid] += v;
        __syncthreads();
    }
    u32 target = qr2[q];
    u32 cum = part[tid] - local;
    if (local && target >= cum && target < cum + local)
        mids[q] = __uint_as_float((((qb1[q] << 10) | qb2[q]) << 10) | (u32)tid);
}

// ---- splat pass: per-target max priority (priority encodes src index) ----
__global__ void k_prio(const float* __restrict__ depth, const float* __restrict__ flow,
                       const int* __restrict__ splitp, const float* __restrict__ mids,
                       u32* __restrict__ prio) {
    int i = blockIdx.x * blockDim.x + threadIdx.x;
    if (i >= NPIX) return;
    float d = depth[i];
    int split = *splitp;
    int rank = -1;
    for (int k = 1; k <= split; ++k) {
        if (d >= mids[k - 1] && d < mids[k]) { rank = split - k; break; }
    }
    if (rank < 0) return;  // includes d == max (strict <) and d == 100 sentinel
    int y = i / WW, x = i - y * WW;
    float2 f = ((const float2*)flow)[i];
    int ty = (int)rintf((float)y + f.y);  // rintf = round-half-even = jnp.round
    int tx = (int)rintf((float)x + f.x);
    if (ty < 0) ty += HH;                 // JAX normalizes negative indices once
    if (tx < 0) tx += WW;
    if ((unsigned)ty >= (unsigned)HH || (unsigned)tx >= (unsigned)WW) return;  // drop
    int t = ty * WW + tx;
    // far bins = low rank; near bins = high; within bin, last row-major wins
    u32 p = (u32)rank * (u32)NPIX + (u32)i + 1u;
    atomicMax(&prio[t], p);
}

// ---- final write, target-indexed: decode winner src from priority ----
__global__ void k_write_out(const u32* __restrict__ prio, const float* __restrict__ img,
                            float* __restrict__ out) {
    int t = blockIdx.x * blockDim.x + threadIdx.x;
    if (t >= NPIX) return;
    u32 p = prio[t];
    float r = 0.f, g = 0.f, b = 0.f;
    if (p) {
        u32 src = (p - 1u) % (u32)NPIX;   // p-1 = rank*NPIX + src
        r = img[src * 3 + 0];
        g = img[src * 3 + 1];
        b = img[src * 3 + 2];
    }
    out[t * 3 + 0] = r;
    out[t * 3 + 1] = g;
    out[t * 3 + 2] = b;
}

extern "C" void kernel_launch(void* const* d_in, const int* in_sizes, int n_in,
                              void* d_out, int out_size, void* d_ws, size_t ws_size,
                              hipStream_t stream) {
    const float* img    = (const float*)d_in[0];
    const float* flow   = (const float*)d_in[1];   // [1,H,W,2] flat == [H,W,2]
    const float* depth  = (const float*)d_in[2];
    const int*   splitp = (const int*)d_in[3];

    char* ws = (char*)d_ws;
    float* mids  = (float*)(ws + MIDS_OFF);
    u32*   qb1   = (u32*)(ws + QB1_OFF);
    u32*   qr1   = (u32*)(ws + QR1_OFF);
    u32*   qb2   = (u32*)(ws + QB2_OFF);
    u32*   qr2   = (u32*)(ws + QR2_OFF);
    u32*   tot1  = (u32*)(ws + TOT1_OFF);
    u32*   hist2 = (u32*)(ws + HIST2_OFF);
    u32*   hist3 = (u32*)(ws + HIST3_OFF);
    u32*   prio  = (u32*)(ws + PRIO_OFF);
    float* out   = (float*)d_out;

    // zero: query scratch + replicated hists + priorities (out written fully by k_write_out)
    hipMemsetAsync(d_ws, 0, ZERO_BYTES, stream);

    int blocks = (NPIX + 255) / 256;
    k_histA    <<<NBLK_A, 256, 0, stream>>>(depth, tot1);
    k_selA     <<<1, 1024, 0, stream>>>(tot1, splitp, qb1, qr1);
    k_histB    <<<blocks, 256, 0, stream>>>(depth, splitp, qb1, hist2);
    k_selB     <<<NQ, 1024, 0, stream>>>(hist2, splitp, qr1, qb2, qr2);
    k_histC    <<<blocks, 256, 0, stream>>>(depth, splitp, qb1, qb2, hist3);
    k_selC     <<<NQ, 1024, 0, stream>>>(hist3, splitp, qb1, qb2, qr2, mids);
    k_prio     <<<blocks, 256, 0, stream>>>(depth, flow, splitp, mids, prio);
    k_write_out<<<blocks, 256, 0, stream>>>(prio, img, out);
}

// Round 4
// 158.552 us; speedup vs baseline: 6.6102x; 1.2225x over previous
//
#include <hip/hip_runtime.h>

typedef unsigned int u32;

static constexpr int HH = 1080, WW = 1920;
static constexpr int NPIX = HH * WW;
static constexpr int NQ = 17;        // supports split <= 16 (actual split = 10)
static constexpr int NBLK_A = 256;   // grid-stride blocks for level-1 histogram
static constexpr int R1 = 16;        // replicas for level-1 / tile-count merges
static constexpr int R2 = 32;        // replicas for level-2/3 hists
static constexpr int TS = 64;        // target tile size
static constexpr int TCX = WW / TS;  // 30
static constexpr int TCY = (HH + TS - 1) / TS;  // 17
static constexpr int NTILE = TCX * TCY;          // 510 (pad to 512)
static constexpr int CUR_STRIDE = 16;            // pad cursors to 1/line

// ---- workspace layout (bytes) ----
static constexpr size_t MIDS_OFF   = 0;      // float[32]
static constexpr size_t QB1_OFF    = 128;    // u32[32]
static constexpr size_t QR1_OFF    = 256;    // u32[32]
static constexpr size_t QB2_OFF    = 384;    // u32[32]
static constexpr size_t QR2_OFF    = 512;    // u32[32]
static constexpr size_t TOT1_OFF   = 1024;                                   // u32[R1*4096]
static constexpr size_t HIST2_OFF  = TOT1_OFF + (size_t)R1 * 4096 * 4;       // u32[R2*NQ*1024]
static constexpr size_t HIST3_OFF  = HIST2_OFF + (size_t)R2 * NQ * 1024 * 4; // u32[R2*NQ*1024]
static constexpr size_t TCNT_OFF   = HIST3_OFF + (size_t)R2 * NQ * 1024 * 4; // u32[R1*512]
static constexpr size_t ZERO_BYTES = TCNT_OFF + (size_t)R1 * 512 * 4;        // memset range
static constexpr size_t TBASE_OFF  = ZERO_BYTES;                             // u32[512]
static constexpr size_t TCUR_OFF   = TBASE_OFF + 512 * 4;                    // u32[512*CUR_STRIDE]
static constexpr size_t PAIRS_OFF  = (TCUR_OFF + (size_t)512 * CUR_STRIDE * 4 + 255) & ~255ull;

// ---- geometry helper: target pixel index, or -1 if dropped (flow-only) ----
__device__ __forceinline__ int target_of(int i, float2 f) {
    int y = i / WW, x = i - y * WW;
    int ty = (int)rintf((float)y + f.y);  // rintf = round-half-even = jnp.round
    int tx = (int)rintf((float)x + f.x);
    if (ty < 0) ty += HH;                 // JAX normalizes negative indices once
    if (tx < 0) tx += WW;
    if ((unsigned)ty >= (unsigned)HH || (unsigned)tx >= (unsigned)WW) return -1;
    return ty * WW + tx;
}

// ---- level 1: LDS 4096-bin histogram of bits[31:20] + per-tile target counts ----
__global__ __launch_bounds__(256) void k_histA_cnt(const float* __restrict__ depth,
                                                   const float* __restrict__ flow,
                                                   u32* __restrict__ tot1,
                                                   u32* __restrict__ tcnt) {
    __shared__ u32 h[4096];
    __shared__ u32 tc[512];
    for (int j = threadIdx.x; j < 4096; j += 256) h[j] = 0;
    for (int j = threadIdx.x; j < 512; j += 256) tc[j] = 0;
    __syncthreads();
    for (int i = blockIdx.x * 256 + threadIdx.x; i < NPIX; i += gridDim.x * 256) {
        float d = depth[i];
        if (d != 100.0f)                                 // sentinel excluded
            atomicAdd(&h[__float_as_uint(d) >> 20], 1u); // d>0 -> bits monotonic
        float2 f = ((const float2*)flow)[i];
        int t = target_of(i, f);
        if (t >= 0) {
            int ty = t / WW, tx = t - ty * WW;
            atomicAdd(&tc[(ty >> 6) * TCX + (tx >> 6)], 1u);
        }
    }
    __syncthreads();
    u32 rep = blockIdx.x & (R1 - 1);
    for (int j = threadIdx.x; j < 4096; j += 256) {
        u32 v = h[j];
        if (v) atomicAdd(&tot1[rep * 4096 + j], v);   // replica-spread sparse merge
    }
    for (int j = threadIdx.x; j < 512; j += 256) {
        u32 v = tc[j];
        if (v) atomicAdd(&tcnt[rep * 512 + j], v);
    }
}

// ---- level-1 select + tile prefix-sum ----
__global__ __launch_bounds__(1024) void k_selA(const u32* __restrict__ tot1,
                                               const int* __restrict__ splitp,
                                               const u32* __restrict__ tcnt,
                                               u32* __restrict__ qb1, u32* __restrict__ qr1,
                                               u32* __restrict__ tbase, u32* __restrict__ tcur) {
    __shared__ u32 part[1024];
    __shared__ u32 totalsh;
    int tid = threadIdx.x;
    int base = tid * 4;
    u32 cc[4] = {0, 0, 0, 0};
    for (int r = 0; r < R1; ++r)
        for (int j = 0; j < 4; ++j) cc[j] += tot1[r * 4096 + base + j];
    u32 local = cc[0] + cc[1] + cc[2] + cc[3];
    part[tid] = local;
    __syncthreads();
    for (int off = 1; off < 1024; off <<= 1) {
        u32 v = (tid >= off) ? part[tid - off] : 0;
        __syncthreads();
        part[tid] += v;
        __syncthreads();
    }
    if (tid == 1023) totalsh = part[1023];
    __syncthreads();
    u32 l = totalsh;                 // valid-pixel count = sum of histogram
    int split = *splitp;
    u32 step = l / (u32)split;
    u32 cum = part[tid] - local;     // exclusive prefix of this thread's 4 bins
    for (int j = 0; j < 4; ++j) {
        u32 c = cc[j];
        if (c) {
            for (int q = 0; q <= split; ++q) {
                u32 r = (q < split) ? (u32)q * step : l - 1u;
                if (r >= cum && r < cum + c) { qb1[q] = (u32)(base + j); qr1[q] = r - cum; }
            }
        }
        cum += c;
    }
    // ---- phase 2: prefix-sum the 512 tile counts -> base & cursor ----
    __syncthreads();
    u32 tval = 0;
    if (tid < 512)
        for (int r = 0; r < R1; ++r) tval += tcnt[r * 512 + tid];
    part[tid] = tval;
    __syncthreads();
    for (int off = 1; off < 1024; off <<= 1) {
        u32 v = (tid >= off) ? part[tid - off] : 0;
        __syncthreads();
        part[tid] += v;
        __syncthreads();
    }
    if (tid < 512) {
        u32 b = part[tid] - tval;    // exclusive prefix
        tbase[tid] = b;
        tcur[tid * CUR_STRIDE] = b;
    }
}

// ---- level 2: 1024-bin histogram of bits[19:10], restricted per query ----
__global__ void k_histB(const float* __restrict__ depth, const int* __restrict__ splitp,
                        const u32* __restrict__ qb1, u32* __restrict__ hist2) {
    int i = blockIdx.x * blockDim.x + threadIdx.x;
    if (i >= NPIX) return;
    float d = depth[i];
    if (d == 100.0f) return;
    u32 bits = __float_as_uint(d);
    u32 b1 = bits >> 20, b2 = (bits >> 10) & 1023u;
    u32 rep = (u32)(threadIdx.x & (R2 - 1));
    int split = *splitp;
    for (int q = 0; q <= split; ++q)
        if (qb1[q] == b1) atomicAdd(&hist2[(rep * NQ + q) * 1024 + b2], 1u);
}

// ---- level-2 select ----
__global__ __launch_bounds__(1024) void k_selB(const u32* __restrict__ hist2,
                                               const int* __restrict__ splitp,
                                               const u32* __restrict__ qr1,
                                               u32* __restrict__ qb2, u32* __restrict__ qr2) {
    int q = blockIdx.x;
    if (q > *splitp) return;
    __shared__ u32 part[1024];
    int tid = threadIdx.x;
    u32 local = 0;
    for (int r = 0; r < R2; ++r) local += hist2[(r * NQ + q) * 1024 + tid];
    part[tid] = local;
    __syncthreads();
    for (int off = 1; off < 1024; off <<= 1) {
        u32 v = (tid >= off) ? part[tid - off] : 0;
        __syncthreads();
        part[tid] += v;
        __syncthreads();
    }
    u32 target = qr1[q];
    u32 cum = part[tid] - local;
    if (local && target >= cum && target < cum + local) {
        qb2[q] = (u32)tid;
        qr2[q] = target - cum;
    }
}

// ---- level 3: 1024-bin histogram of bits[9:0], restricted to 22-bit key ----
__global__ void k_histC(const float* __restrict__ depth, const int* __restrict__ splitp,
                        const u32* __restrict__ qb1, const u32* __restrict__ qb2,
                        u32* __restrict__ hist3) {
    int i = blockIdx.x * blockDim.x + threadIdx.x;
    if (i >= NPIX) return;
    float d = depth[i];
    if (d == 100.0f) return;
    u32 bits = __float_as_uint(d);
    u32 hi22 = bits >> 10;
    u32 rep = (u32)(threadIdx.x & (R2 - 1));
    int split = *splitp;
    for (int q = 0; q <= split; ++q)
        if (((qb1[q] << 10) | qb2[q]) == hi22)
            atomicAdd(&hist3[(rep * NQ + q) * 1024 + (bits & 1023u)], 1u);
}

// ---- level-3 select: exact order-statistic float values ----
__global__ __launch_bounds__(1024) void k_selC(const u32* __restrict__ hist3,
                                               const int* __restrict__ splitp,
                                               const u32* __restrict__ qb1,
                                               const u32* __restrict__ qb2,
                                               const u32* __restrict__ qr2,
                                               float* __restrict__ mids) {
    int q = blockIdx.x;
    if (q > *splitp) return;
    __shared__ u32 part[1024];
    int tid = threadIdx.x;
    u32 local = 0;
    for (int r = 0; r < R2; ++r) local += hist3[(r * NQ + q) * 1024 + tid];
    part[tid] = local;
    __syncthreads();
    for (int off = 1; off < 1024; off <<= 1) {
        u32 v = (tid >= off) ? part[tid - off] : 0;
        __syncthreads();
        part[tid] += v;
        __syncthreads();
    }
    u32 target = qr2[q];
    u32 cum = part[tid] - local;
    if (local && target >= cum && target < cum + local)
        mids[q] = __uint_as_float((((qb1[q] << 10) | qb2[q]) << 10) | (u32)tid);
}

// ---- scatter: (t, p) pairs into contiguous per-tile slots, no per-pixel device atomics ----
__global__ __launch_bounds__(256) void k_scatter(const float* __restrict__ depth,
                                                 const float* __restrict__ flow,
                                                 const int* __restrict__ splitp,
                                                 const float* __restrict__ mids,
                                                 u32* __restrict__ tcur,
                                                 uint2* __restrict__ pairs) {
    __shared__ u32 cnt[512];
    __shared__ u32 basel[512];
    int tid = threadIdx.x;
    for (int j = tid; j < 512; j += 256) cnt[j] = 0;
    __syncthreads();
    int i = blockIdx.x * 256 + tid;   // grid covers NPIX exactly
    float d = depth[i];
    int split = *splitp;
    int rank = -1;
    for (int k = 1; k <= split; ++k) {
        if (d >= mids[k - 1] && d < mids[k]) { rank = split - k; break; }
    }
    float2 f = ((const float2*)flow)[i];
    int t = target_of(i, f);
    int tile = -1;
    u32 loc = 0;
    if (rank >= 0 && t >= 0) {
        int ty = t / WW, tx = t - ty * WW;
        tile = (ty >> 6) * TCX + (tx >> 6);
        loc = atomicAdd(&cnt[tile], 1u);       // LDS
    }
    __syncthreads();
    for (int j = tid; j < 512; j += 256) {
        u32 c = cnt[j];
        if (c) basel[j] = atomicAdd(&tcur[j * CUR_STRIDE], c);  // ~12 device atomics/block
    }
    __syncthreads();
    if (tile >= 0) {
        // far bins = low rank; near bins = high; within bin, last row-major wins
        u32 p = (u32)rank * (u32)NPIX + (u32)i + 1u;
        pairs[basel[tile] + loc] = make_uint2((u32)t, p);
    }
}

// ---- per-tile LDS z-buffer reduce + output write ----
__global__ __launch_bounds__(256) void k_tile_reduce(const uint2* __restrict__ pairs,
                                                     const u32* __restrict__ tbase,
                                                     const u32* __restrict__ tcur,
                                                     const float* __restrict__ img,
                                                     float* __restrict__ out) {
    __shared__ u32 zb[TS * TS];
    int tid = threadIdx.x;
    int tile = blockIdx.x;
    for (int c = tid; c < TS * TS; c += 256) zb[c] = 0;
    __syncthreads();
    int ty0 = (tile / TCX) << 6, tx0 = (tile % TCX) << 6;
    u32 b = tbase[tile], e = tcur[tile * CUR_STRIDE];
    for (u32 k = b + tid; k < e; k += 256) {
        uint2 pr = pairs[k];
        int t = (int)pr.x;
        int ty = t / WW, tx = t - ty * WW;
        atomicMax(&zb[((ty - ty0) << 6) | (tx - tx0)], pr.y);   // LDS
    }
    __syncthreads();
    for (int c = tid; c < TS * TS; c += 256) {
        int ty = ty0 + (c >> 6);
        if (ty >= HH) continue;
        int tx = tx0 + (c & 63);
        u32 p = zb[c];
        float r = 0.f, g = 0.f, bl = 0.f;
        if (p) {
            u32 src = (p - 1u) % (u32)NPIX;   // p-1 = rank*NPIX + src
            r  = img[src * 3 + 0];
            g  = img[src * 3 + 1];
            bl = img[src * 3 + 2];
        }
        int t = ty * WW + tx;
        out[t * 3 + 0] = r;
        out[t * 3 + 1] = g;
        out[t * 3 + 2] = bl;
    }
}

extern "C" void kernel_launch(void* const* d_in, const int* in_sizes, int n_in,
                              void* d_out, int out_size, void* d_ws, size_t ws_size,
                              hipStream_t stream) {
    const float* img    = (const float*)d_in[0];
    const float* flow   = (const float*)d_in[1];   // [1,H,W,2] flat == [H,W,2]
    const float* depth  = (const float*)d_in[2];
    const int*   splitp = (const int*)d_in[3];

    char* ws = (char*)d_ws;
    float* mids  = (float*)(ws + MIDS_OFF);
    u32*   qb1   = (u32*)(ws + QB1_OFF);
    u32*   qr1   = (u32*)(ws + QR1_OFF);
    u32*   qb2   = (u32*)(ws + QB2_OFF);
    u32*   qr2   = (u32*)(ws + QR2_OFF);
    u32*   tot1  = (u32*)(ws + TOT1_OFF);
    u32*   hist2 = (u32*)(ws + HIST2_OFF);
    u32*   hist3 = (u32*)(ws + HIST3_OFF);
    u32*   tcnt  = (u32*)(ws + TCNT_OFF);
    u32*   tbase = (u32*)(ws + TBASE_OFF);
    u32*   tcur  = (u32*)(ws + TCUR_OFF);
    uint2* pairs = (uint2*)(ws + PAIRS_OFF);
    float* out   = (float*)d_out;

    // zero: query scratch + replicated hists + tile counts (~4.7 MB)
    hipMemsetAsync(d_ws, 0, ZERO_BYTES, stream);

    int blocks = NPIX / 256;   // 8100 exactly
    k_histA_cnt  <<<NBLK_A, 256, 0, stream>>>(depth, flow, tot1, tcnt);
    k_selA       <<<1, 1024, 0, stream>>>(tot1, splitp, tcnt, qb1, qr1, tbase, tcur);
    k_histB      <<<blocks, 256, 0, stream>>>(depth, splitp, qb1, hist2);
    k_selB       <<<NQ, 1024, 0, stream>>>(hist2, splitp, qr1, qb2, qr2);
    k_histC      <<<blocks, 256, 0, stream>>>(depth, splitp, qb1, qb2, hist3);
    k_selC       <<<NQ, 1024, 0, stream>>>(hist3, splitp, qb1, qb2, qr2, mids);
    k_scatter    <<<blocks, 256, 0, stream>>>(depth, flow, splitp, mids, tcur, pairs);
    k_tile_reduce<<<NTILE, 256, 0, stream>>>(pairs, tbase, tcur, img, out);
}